// Round 7
// baseline (5601.887 us; speedup 1.0000x reference)
//
#include <hip/hip_runtime.h>
#include <hip/hip_cooperative_groups.h>
#include <math.h>

namespace cg = cooperative_groups;

typedef unsigned short ushort_t;
typedef __attribute__((ext_vector_type(8))) short bf16x8;
typedef __attribute__((ext_vector_type(4))) float f32x4;

constexpr int Bb  = 128;
constexpr int Ll  = 196;
constexpr int ENCe= 512;
constexpr int Hh  = 512;
constexpr int Ee  = 256;
constexpr int Vv  = 10000;
constexpr int Tt  = 20;

#define DEV __device__ __forceinline__

DEV float sigm_f(float x) { return 1.f / (1.f + __expf(-x)); }
DEV float tanh_f(float x) {
    x = fminf(fmaxf(x, -15.f), 15.f);
    float e = __expf(2.f * x);
    return (e - 1.f) / (e + 1.f);
}
DEV ushort_t f2bf(float v) {
    unsigned u = __float_as_uint(v);
    return (ushort_t)((u + 0x7FFFu + ((u >> 16) & 1u)) >> 16);
}
DEV float bf2f(ushort_t h) { return __uint_as_float(((unsigned)h) << 16); }

// Packed-fragment layout for a logical [R][K] bf16 matrix:
//   (r,k) -> ((r>>4)*KS + (k>>5))*512 + (((k>>3)&3)*16 + (r&15))*8 + (k&7)
DEV void store_xh(ushort_t* __restrict__ H, ushort_t* __restrict__ L,
                  int b, int k, float v)
{
    size_t idx = (((size_t)(b >> 4) * 40 + (k >> 5)) * 64
                  + ((k >> 3) & 3) * 16 + (b & 15)) * 8 + (k & 7);
    ushort_t hb = f2bf(v);
    H[idx] = hb;
    L[idx] = f2bf(v - bf2f(hb));
}

// ---------------------------------------------------------------------------
// fp32 tiled GEMM (h0/c0 + enc_proj fallback). OUTBF emits bf16.
// ---------------------------------------------------------------------------
template<int BN, int TM, int TN, int ACT1, int OUTBF>
__global__ __launch_bounds__(256)
void gemm_k(const float* __restrict__ A, int lda,
            const float* __restrict__ Wk, int ldw,
            const float* __restrict__ bias,
            void* __restrict__ Cv, long long ldc,
            int M, int N, int K)
{
    constexpr int BM = 64, BK = 16;
    constexpr int TX = BN / TN, TY = BM / TM;
    static_assert(TX * TY == 256, "bad tile config");
    __shared__ float As[BK][BM];
    __shared__ float Ws[BK][BN];

    const int tid = threadIdx.x;
    const int tx = tid % TX, ty = tid / TX;
    const int nb = blockIdx.x * BN, mb = blockIdx.y * BM;

    float acc[TM][TN] = {};
    const int am = tid >> 2;
    const int ak = (tid & 3) * 4;
    const int wn = tid % BN;
    const int wk0 = tid / BN;
    constexpr int WKSTEP = 256 / BN;

    for (int k0 = 0; k0 < K; k0 += BK) {
        float4 av = *(const float4*)&A[(size_t)(mb + am) * lda + k0 + ak];
        As[ak + 0][am] = av.x;
        As[ak + 1][am] = av.y;
        As[ak + 2][am] = av.z;
        As[ak + 3][am] = av.w;
        #pragma unroll
        for (int i = 0; i < BK / WKSTEP; ++i) {
            int kw = wk0 + i * WKSTEP;
            Ws[kw][wn] = (nb + wn < N) ? Wk[(size_t)(k0 + kw) * ldw + nb + wn] : 0.f;
        }
        __syncthreads();
        #pragma unroll
        for (int k = 0; k < BK; ++k) {
            float a[TM], w[TN];
            #pragma unroll
            for (int i = 0; i < TM; ++i) a[i] = As[k][ty * TM + i];
            #pragma unroll
            for (int j = 0; j < TN; ++j) w[j] = Ws[k][tx * TN + j];
            #pragma unroll
            for (int i = 0; i < TM; ++i)
                #pragma unroll
                for (int j = 0; j < TN; ++j)
                    acc[i][j] = fmaf(a[i], w[j], acc[i][j]);
        }
        __syncthreads();
    }

    #pragma unroll
    for (int i = 0; i < TM; ++i) {
        int m = mb + ty * TM + i;
        #pragma unroll
        for (int j = 0; j < TN; ++j) {
            int n = nb + tx * TN + j;
            if (n < N) {
                float v = acc[i][j];
                if (bias) v += bias[n];
                if (ACT1 == 1) v = tanh_f(v);
                if (OUTBF) ((ushort_t*)Cv)[(size_t)m * ldc + n] = f2bf(v);
                else       ((float*)Cv)[(size_t)m * ldc + n] = v;
            }
        }
    }
}

// ---------------------------------------------------------------------------
// Packed-fragment MFMA GEMM with register double-buffer prefetch.
// (enc_proj hi-only + batched logits)
// ---------------------------------------------------------------------------
template<int MT, int NT, int ACT1, int ACT2, int SPLIT, bool OUTBF, bool PERM,
         bool XSWZ, bool NMINOR, bool W2D>
__global__ __launch_bounds__(256)
void mgemm_pk(const ushort_t* __restrict__ AH, const ushort_t* __restrict__ AL, int aFS,
              const ushort_t* __restrict__ BH, const ushort_t* __restrict__ BL, int bFS,
              const float* __restrict__ bias, const float* __restrict__ bias2, int N1,
              void* __restrict__ Cv, long long ldc, long long ldc2,
              int Nfrags, int Ntot, int nsteps, int bdiv)
{
    int bx, by;
    if (XSWZ) {
        int nwg = gridDim.x, orig = blockIdx.x;
        int xcd = orig & 7, idx = orig >> 3;
        int q = nwg >> 3, r = nwg & 7;
        int lin = (xcd < r ? xcd * (q + 1) : r * (q + 1) + (xcd - r) * q) + idx;
        int l1 = lin / bdiv, l2 = lin - l1 * bdiv;
        bx = NMINOR ? l2 : l1;
        by = NMINOR ? l1 : l2;
    } else { bx = blockIdx.x; by = blockIdx.y; }

    const int wv = threadIdx.x >> 6, lane = threadIdx.x & 63;
    int nf0, mf0;
    if (W2D) {
        nf0 = (bx * 2 + (wv & 1)) * NT;
        mf0 = by * (2 * MT) + (wv >> 1) * MT;
    } else {
        nf0 = (bx * 4 + wv) * NT;
        mf0 = by * MT;
    }
    if (nf0 >= Nfrags) return;
    const int col = lane & 15;
    const int lofs = lane * 8;

    const ushort_t *paH[MT], *paL[MT], *pbH[NT], *pbL[NT];
    #pragma unroll
    for (int mt = 0; mt < MT; ++mt) {
        paH[mt] = AH + (size_t)(mf0 + mt) * aFS + lofs;
        paL[mt] = (SPLIT >= 2) ? (AL + (size_t)(mf0 + mt) * aFS + lofs) : paH[mt];
    }
    #pragma unroll
    for (int ct = 0; ct < NT; ++ct) {
        int nf = nf0 + ct; if (nf > Nfrags - 1) nf = Nfrags - 1;
        pbH[ct] = BH + (size_t)nf * bFS + lofs;
        pbL[ct] = (SPLIT == 3) ? (BL + (size_t)nf * bFS + lofs) : pbH[ct];
    }

    f32x4 acc[MT][NT];
    #pragma unroll
    for (int mt = 0; mt < MT; ++mt)
        #pragma unroll
        for (int ct = 0; ct < NT; ++ct) acc[mt][ct] = (f32x4){0.f, 0.f, 0.f, 0.f};

    auto LOADF = [&](bf16x8 (&A0)[MT], bf16x8 (&A1)[MT],
                     bf16x8 (&B0)[NT], bf16x8 (&B1)[NT], int i) {
        size_t o = (size_t)i * 512;
        #pragma unroll
        for (int mt = 0; mt < MT; ++mt) {
            A0[mt] = *(const bf16x8*)(paH[mt] + o);
            if (SPLIT >= 2) A1[mt] = *(const bf16x8*)(paL[mt] + o);
        }
        #pragma unroll
        for (int ct = 0; ct < NT; ++ct) {
            B0[ct] = *(const bf16x8*)(pbH[ct] + o);
            if (SPLIT == 3) B1[ct] = *(const bf16x8*)(pbL[ct] + o);
        }
    };
    auto COMPF = [&](bf16x8 (&A0)[MT], bf16x8 (&A1)[MT],
                     bf16x8 (&B0)[NT], bf16x8 (&B1)[NT]) {
        #pragma unroll
        for (int mt = 0; mt < MT; ++mt)
            #pragma unroll
            for (int ct = 0; ct < NT; ++ct) {
                acc[mt][ct] = __builtin_amdgcn_mfma_f32_16x16x32_bf16(A0[mt], B0[ct], acc[mt][ct], 0, 0, 0);
                if (SPLIT >= 2)
                    acc[mt][ct] = __builtin_amdgcn_mfma_f32_16x16x32_bf16(A1[mt], B0[ct], acc[mt][ct], 0, 0, 0);
                if (SPLIT == 3)
                    acc[mt][ct] = __builtin_amdgcn_mfma_f32_16x16x32_bf16(A0[mt], B1[ct], acc[mt][ct], 0, 0, 0);
            }
    };

    bf16x8 xa0[MT], xa1[MT], xb0[NT], xb1[NT];
    bf16x8 ya0[MT], ya1[MT], yb0[NT], yb1[NT];
    LOADF(xa0, xa1, xb0, xb1, 0);
    for (int i = 0; i < nsteps; i += 2) {
        LOADF(ya0, ya1, yb0, yb1, i + 1);
        COMPF(xa0, xa1, xb0, xb1);
        if (i + 2 < nsteps) LOADF(xa0, xa1, xb0, xb1, i + 2);
        COMPF(ya0, ya1, yb0, yb1);
    }

    #pragma unroll
    for (int ct = 0; ct < NT; ++ct) {
        const int nc = (nf0 + ct) * 16 + col;
        if (nc >= Ntot) continue;
        const bool ns = ((nf0 + ct) * 16 >= N1);
        float bv = ns ? (bias2 ? bias2[nc - N1] : 0.f) : (bias ? bias[nc] : 0.f);
        const int act = ns ? ACT2 : ACT1;
        #pragma unroll
        for (int mt = 0; mt < MT; ++mt)
            #pragma unroll
            for (int r = 0; r < 4; ++r) {
                int row = (mf0 + mt) * 16 + (lane >> 4) * 4 + r;
                float v = acc[mt][ct][r] + bv;
                if (act == 1)      v = tanh_f(v);
                else if (act == 2) v = sigm_f(v);
                size_t off = PERM ? ((size_t)(row & 127) * ldc + (size_t)(row >> 7) * ldc2 + nc)
                                  : ((size_t)row * ldc + nc);
                if (OUTBF)      ((ushort_t*)Cv)[off] = f2bf(v);
                else if (PERM)  __builtin_nontemporal_store(v, &((float*)Cv)[off]);
                else            ((float*)Cv)[off] = v;
            }
    }
}

// ---------------------------------------------------------------------------
// Weight transpose+convert into PACKED-FRAGMENT layout.
// ---------------------------------------------------------------------------
template<bool LO>
__global__ __launch_bounds__(256)
void convT_pk(const float* __restrict__ W, int N, int KSr,
              ushort_t* __restrict__ PH, ushort_t* __restrict__ PL,
              int KSfull, int ksOfs, int nfOfs)
{
    int tid = blockIdx.x * 256 + threadIdx.x;
    int lane = tid & 63;
    int rest = tid >> 6;
    int ks = rest % KSr;
    int nf = rest / KSr;
    const float* src = W + (size_t)(ks * 32 + ((lane >> 4) & 3) * 8) * N
                         + nf * 16 + (lane & 15);
    size_t dbase = (((size_t)(nf + nfOfs) * KSfull + ks + ksOfs) * 64 + lane) * 8;
    #pragma unroll
    for (int jj = 0; jj < 8; ++jj) {
        float v = src[(size_t)jj * N];
        ushort_t h = f2bf(v);
        PH[dbase + jj] = h;
        if (LO) PL[dbase + jj] = f2bf(v - bf2f(h));
    }
}

// img fp32 -> linear bf16 hi + packed bf16 hi
__global__ __launch_bounds__(256)
void convimg_k(const float* __restrict__ img, ushort_t* __restrict__ linH,
               ushort_t* __restrict__ pkH)
{
    int tid = blockIdx.x * 256 + threadIdx.x;
    int lane = tid & 63;
    int rest = tid >> 6;
    int ks = rest & 15, rf = rest >> 4;
    int r = rf * 16 + (lane & 15);
    int k = ks * 32 + ((lane >> 4) & 3) * 8;
    const float* src = img + (size_t)r * 512 + k;
    ushort_t* ld = linH + (size_t)r * 512 + k;
    size_t pidx = (((size_t)rf * 16 + ks) * 64 + lane) * 8;
    #pragma unroll
    for (int jj = 0; jj < 8; ++jj) {
        ushort_t h = f2bf(src[jj]);
        ld[jj] = h;
        pkH[pidx + jj] = h;
    }
}

__global__ void convbf_k(const float* __restrict__ src, ushort_t* __restrict__ dst,
                         long long n)
{
    long long i = (long long)(blockIdx.x * 256 + threadIdx.x) * 4;
    long long stride = (long long)gridDim.x * 1024;
    for (; i + 3 < n; i += stride) {
        float4 v = *(const float4*)&src[i];
        dst[i + 0] = f2bf(v.x); dst[i + 1] = f2bf(v.y);
        dst[i + 2] = f2bf(v.z); dst[i + 3] = f2bf(v.w);
    }
}

__global__ __launch_bounds__(256)
void featmean_k(const float* __restrict__ img, float* __restrict__ fm)
{
    int b = blockIdx.x, tid = threadIdx.x;
    const float* base = img + (size_t)b * Ll * ENCe;
    for (int e = tid; e < ENCe; e += 256) {
        float s = 0.f;
        for (int l = 0; l < Ll; ++l) s += base[l * ENCe + e];
        fm[b * ENCe + e] = s * (1.f / (float)Ll);
    }
}

__global__ void bcomb_k(const float* __restrict__ bih, const float* __restrict__ bhh,
                        float* __restrict__ bc)
{
    int i = blockIdx.x * 256 + threadIdx.x;
    if (i < 4 * Hh) bc[i] = bih[i] + bhh[i];
}

__global__ void hconv_k(const float* __restrict__ h, ushort_t* __restrict__ xhi,
                        ushort_t* __restrict__ xlo)
{
    int i = blockIdx.x * 256 + threadIdx.x;
    if (i >= Bb * Hh) return;
    int b = i / Hh, j = i % Hh;
    store_xh(xhi, xlo, b, 768 + j, h[i]);
}

// ---------------------------------------------------------------------------
// Persistent-loop parameter block + per-step phases (device functions)
// ---------------------------------------------------------------------------
struct LP {
    const ushort_t *WdgH, *WdgL, *WgH, *WgL, *enc, *imgLin;
    const float    *imgF, *v_att, *emb;
    const int      *captions;
    const float    *b_ad, *b_gate, *bcomb;
    float          *dgb, *cbuf, *alphas;
    ushort_t       *xhH, *xhL, *hsH, *hsL;
};

// P1: dg = [h@W_ad + b_ad | sigmoid(h@W_gate + b_gate)]   (256 blocks)
DEV void phase_dg(const LP& P, int beta, char* smem)
{
    const int tid = threadIdx.x, wv = tid >> 6, lane = tid & 63;
    const int bx = beta >> 3, mf = beta & 7;
    const int nf = bx * 2 + (wv & 1), kh = wv >> 1;
    const int lofs = lane * 8;
    const bool blo = (P.WdgL != nullptr);

    const ushort_t* paH = P.xhH + ((size_t)mf * 40 + 24 + kh * 8) * 512 + lofs;
    const ushort_t* paL = P.xhL + ((size_t)mf * 40 + 24 + kh * 8) * 512 + lofs;
    const ushort_t* pbH = P.WdgH + ((size_t)nf * 16 + kh * 8) * 512 + lofs;
    const ushort_t* pbL = blo ? (P.WdgL + ((size_t)nf * 16 + kh * 8) * 512 + lofs) : pbH;

    f32x4 acc = (f32x4){0.f, 0.f, 0.f, 0.f};
    #pragma unroll
    for (int i = 0; i < 8; ++i) {
        size_t o = (size_t)i * 512;
        bf16x8 A0 = *(const bf16x8*)(paH + o);
        bf16x8 A1 = *(const bf16x8*)(paL + o);
        bf16x8 B0 = *(const bf16x8*)(pbH + o);
        acc = __builtin_amdgcn_mfma_f32_16x16x32_bf16(A0, B0, acc, 0, 0, 0);
        acc = __builtin_amdgcn_mfma_f32_16x16x32_bf16(A1, B0, acc, 0, 0, 0);
        if (blo) {
            bf16x8 B1 = *(const bf16x8*)(pbL + o);
            acc = __builtin_amdgcn_mfma_f32_16x16x32_bf16(A0, B1, acc, 0, 0, 0);
        }
    }

    f32x4* part = (f32x4*)smem;   // [2][64]
    if (kh == 1) part[(wv & 1) * 64 + lane] = acc;
    __syncthreads();
    if (kh == 0) {
        acc += part[(wv & 1) * 64 + lane];
        int n = nf * 16 + (lane & 15);
        float bv = (n < 512) ? P.b_ad[n] : P.b_gate[n - 512];
        #pragma unroll
        for (int r = 0; r < 4; ++r) {
            int row = mf * 16 + (lane >> 4) * 4 + r;
            float v = acc[r] + bv;
            if (n >= 512) v = sigm_f(v);
            P.dgb[row * 1024 + n] = v;
        }
    }
}

// P2: attention (score->softmax->alphas/emb->ctx*gate) — blocks 0..127 active
DEV void phase_attn(const LP& P, int t, int beta, char* smem)
{
    if (beta >= 128) return;
    const int b = beta;
    const int tid = threadIdx.x, wv = tid >> 6, ln = tid & 63;
    float* dp  = (float*)smem;     // 512
    float* va  = dp + 512;         // 512
    float* es  = va + 512;         // 208
    float* red = es + 208;         // 8

    dp[tid]       = P.dgb[b * 1024 + tid];
    dp[tid + 256] = P.dgb[b * 1024 + tid + 256];
    va[tid]       = P.v_att[tid];
    va[tid + 256] = P.v_att[tid + 256];
    __syncthreads();

    const ushort_t* ep = P.enc + (size_t)b * Ll * Hh;
    for (int l = wv; l < Ll; l += 4) {
        const ushort_t* row = ep + (size_t)l * Hh;
        float s = 0.f;
        #pragma unroll
        for (int r = 0; r < 8; ++r) {
            int k = r * 64 + ln;
            s += tanh_f(bf2f(row[k]) + dp[k]) * va[k];
        }
        #pragma unroll
        for (int o = 32; o; o >>= 1) s += __shfl_xor(s, o);
        if (ln == 0) es[l] = s;
    }
    __syncthreads();

    float v = (tid < Ll) ? es[tid] : -1e30f;
    float m = v;
    #pragma unroll
    for (int o = 32; o; o >>= 1) m = fmaxf(m, __shfl_xor(m, o));
    if (ln == 0) red[wv] = m;
    __syncthreads();
    m = fmaxf(fmaxf(red[0], red[1]), fmaxf(red[2], red[3]));
    __syncthreads();
    float pp = (tid < Ll) ? __expf(v - m) : 0.f;
    float ssum = pp;
    #pragma unroll
    for (int o = 32; o; o >>= 1) ssum += __shfl_xor(ssum, o);
    if (ln == 0) red[wv] = ssum;
    __syncthreads();
    ssum = red[0] + red[1] + red[2] + red[3];
    float inv = 1.f / ssum;
    if (tid < Ll) {
        float a = pp * inv;
        es[tid] = a;
        P.alphas[(size_t)b * (Tt * Ll) + t * Ll + tid] = a;
    }
    // emb -> x[0:256]
    {
        float xv = P.emb[(size_t)P.captions[b * Tt + t] * Ee + tid];
        store_xh(P.xhH, P.xhL, b, tid, xv);
    }
    __syncthreads();

    // ctx: 2 e-columns per thread
    float a0 = 0.f, a1 = 0.f;
    if (P.imgLin) {
        const ushort_t* ib = P.imgLin + (size_t)b * Ll * ENCe;
        #pragma unroll 4
        for (int l = 0; l < Ll; ++l) {
            float al = es[l];
            a0 = fmaf(al, bf2f(ib[(size_t)l * ENCe + tid]), a0);
            a1 = fmaf(al, bf2f(ib[(size_t)l * ENCe + tid + 256]), a1);
        }
    } else {
        const float* ib = P.imgF + (size_t)b * Ll * ENCe;
        #pragma unroll 4
        for (int l = 0; l < Ll; ++l) {
            float al = es[l];
            a0 = fmaf(al, ib[(size_t)l * ENCe + tid], a0);
            a1 = fmaf(al, ib[(size_t)l * ENCe + tid + 256], a1);
        }
    }
    float g0 = P.dgb[b * 1024 + 512 + tid];
    float g1 = P.dgb[b * 1024 + 768 + tid];
    store_xh(P.xhH, P.xhL, b, 256 + tid, a0 * g0);
    store_xh(P.xhH, P.xhL, b, 512 + tid, a1 * g1);
}

// P3: gates GEMM (K-split 4 waves) + fused LSTM  (256 blocks: 32 jf x 8 mq)
DEV void phase_gates(const LP& P, int t, int beta, char* smem)
{
    const int tid = threadIdx.x, wv = tid >> 6, lane = tid & 63;
    const int jf = beta & 31, mq = beta >> 5;
    const int ks0 = wv * 10, lofs = lane * 8;
    const bool blo = (P.WgL != nullptr);
    constexpr int FS = 40 * 512;

    const ushort_t* paH = P.xhH + ((size_t)mq * 40 + ks0) * 512 + lofs;
    const ushort_t* paL = P.xhL + ((size_t)mq * 40 + ks0) * 512 + lofs;
    const ushort_t *pbH[4], *pbL[4];
    #pragma unroll
    for (int g = 0; g < 4; ++g) {
        size_t off = (size_t)(g * 32 + jf) * FS + (size_t)ks0 * 512 + lofs;
        pbH[g] = P.WgH + off;
        pbL[g] = blo ? (P.WgL + off) : (P.WgH + off);
    }

    f32x4 acc[4];
    #pragma unroll
    for (int g = 0; g < 4; ++g) acc[g] = (f32x4){0.f, 0.f, 0.f, 0.f};

    auto LOADF = [&](bf16x8 (&A)[2], bf16x8 (&B)[4][2], int i) {
        size_t o = (size_t)i * 512;
        A[0] = *(const bf16x8*)(paH + o);
        A[1] = *(const bf16x8*)(paL + o);
        #pragma unroll
        for (int g = 0; g < 4; ++g) {
            B[g][0] = *(const bf16x8*)(pbH[g] + o);
            if (blo) B[g][1] = *(const bf16x8*)(pbL[g] + o);
        }
    };
    auto COMPF = [&](bf16x8 (&A)[2], bf16x8 (&B)[4][2]) {
        #pragma unroll
        for (int g = 0; g < 4; ++g) {
            acc[g] = __builtin_amdgcn_mfma_f32_16x16x32_bf16(A[0], B[g][0], acc[g], 0, 0, 0);
            acc[g] = __builtin_amdgcn_mfma_f32_16x16x32_bf16(A[1], B[g][0], acc[g], 0, 0, 0);
            if (blo)
                acc[g] = __builtin_amdgcn_mfma_f32_16x16x32_bf16(A[0], B[g][1], acc[g], 0, 0, 0);
        }
    };

    bf16x8 xA[2], xB[4][2], yA[2], yB[4][2];
    LOADF(xA, xB, 0);
    for (int i = 0; i < 10; i += 2) {
        LOADF(yA, yB, i + 1);
        COMPF(xA, xB);
        if (i + 2 < 10) LOADF(xA, xB, i + 2);
        COMPF(yA, yB);
    }

    f32x4* part = (f32x4*)smem;   // [3][4][64]
    if (wv > 0) {
        #pragma unroll
        for (int g = 0; g < 4; ++g) part[((wv - 1) * 4 + g) * 64 + lane] = acc[g];
    }
    __syncthreads();
    if (wv == 0) {
        #pragma unroll
        for (int g = 0; g < 4; ++g) {
            acc[g] += part[(0 * 4 + g) * 64 + lane];
            acc[g] += part[(1 * 4 + g) * 64 + lane];
            acc[g] += part[(2 * 4 + g) * 64 + lane];
        }
        const int j = jf * 16 + (lane & 15);
        float bi = P.bcomb[j], bf_ = P.bcomb[512 + j];
        float bg = P.bcomb[1024 + j], bo = P.bcomb[1536 + j];
        #pragma unroll
        for (int r = 0; r < 4; ++r) {
            int b = mq * 16 + (lane >> 4) * 4 + r;
            float ig = sigm_f(acc[0][r] + bi);
            float fg = sigm_f(acc[1][r] + bf_);
            float gg = tanh_f(acc[2][r] + bg);
            float og = sigm_f(acc[3][r] + bo);
            float cn = fg * P.cbuf[b * 512 + j] + ig * gg;
            P.cbuf[b * 512 + j] = cn;
            float hv = og * tanh_f(cn);
            store_xh(P.xhH, P.xhL, b, 768 + j, hv);
            ushort_t hb = f2bf(hv);
            size_t hidx = (((size_t)(t * 8 + (b >> 4)) * 16 + (j >> 5)) * 64
                           + ((j >> 3) & 3) * 16 + (b & 15)) * 8 + (j & 7);
            P.hsH[hidx] = hb;
            P.hsL[hidx] = f2bf(hv - bf2f(hb));
        }
    }
}

// Persistent cooperative kernel: whole 20-step loop, 3 grid syncs per step.
__global__ __launch_bounds__(256, 1)
void loop_coop_k(LP P)
{
    __shared__ f32x4 smemv[800];   // 12.8 KB, reused across phases
    char* smem = (char*)smemv;
    cg::grid_group grid = cg::this_grid();
    const int beta = blockIdx.x;
    for (int t = 0; t < Tt; ++t) {
        phase_dg(P, beta, smem);
        grid.sync();
        phase_attn(P, t, beta, smem);
        grid.sync();
        phase_gates(P, t, beta, smem);
        grid.sync();
    }
}

// Fallback per-phase kernels (used only if cooperative launch is unavailable)
__global__ __launch_bounds__(256) void ph_dg_k(LP P)
{ __shared__ f32x4 s[800]; phase_dg(P, blockIdx.x, (char*)s); }
__global__ __launch_bounds__(256) void ph_attn_k(LP P, int t)
{ __shared__ f32x4 s[800]; phase_attn(P, t, blockIdx.x, (char*)s); }
__global__ __launch_bounds__(256) void ph_gates_k(LP P, int t)
{ __shared__ f32x4 s[800]; phase_gates(P, t, blockIdx.x, (char*)s); }

// ---------------------------------------------------------------------------
extern "C" void kernel_launch(void* const* d_in, const int* in_sizes, int n_in,
                              void* d_out, int out_size, void* d_ws, size_t ws_size,
                              hipStream_t stream)
{
    const float* img    = (const float*)d_in[0];
    const float* W_h    = (const float*)d_in[1];
    const float* b_h    = (const float*)d_in[2];
    const float* W_c    = (const float*)d_in[3];
    const float* b_c    = (const float*)d_in[4];
    const float* W_gate = (const float*)d_in[5];
    const float* b_gate = (const float*)d_in[6];
    const float* emb    = (const float*)d_in[7];
    const float* W_ae   = (const float*)d_in[8];
    const float* b_ae   = (const float*)d_in[9];
    const float* W_ad   = (const float*)d_in[10];
    const float* b_ad   = (const float*)d_in[11];
    const float* v_att  = (const float*)d_in[12];
    const float* W_ih   = (const float*)d_in[14];
    const float* b_ih   = (const float*)d_in[15];
    const float* W_hh   = (const float*)d_in[16];
    const float* b_hh   = (const float*)d_in[17];
    const float* W_out  = (const float*)d_in[18];
    const float* b_out  = (const float*)d_in[19];
    const int* captions = (const int*)d_in[20];

    float* out    = (float*)d_out;                       // [B,T,V]
    float* alphas = out + (size_t)Bb * Tt * Vv;          // [B,T,L]

    // ---- workspace allocator (256B aligned) ----
    char* p = (char*)d_ws;
    auto alloc = [&](size_t bytes) -> char* {
        char* r = p; p += (bytes + 255) & ~(size_t)255; return r;
    };
    const size_t szEnc   = (size_t)Bb * Ll * Hh * 2;
    const size_t szWout  = (size_t)625 * 16 * 512 * 2;
    const size_t szWg    = (size_t)128 * 40 * 512 * 2;
    const size_t szWdg   = (size_t)64 * 16 * 512 * 2;
    const size_t szWae   = (size_t)32 * 16 * 512 * 2;
    const size_t szXh    = (size_t)8 * 40 * 512 * 2;
    const size_t szHseq  = (size_t)160 * 16 * 512 * 2;
    const size_t szImg   = (size_t)Bb * Ll * ENCe * 2;

    ushort_t* enc_hi  = (ushort_t*)alloc(szEnc);
    ushort_t* WoutPkH = (ushort_t*)alloc(szWout);
    ushort_t* WgPkH   = (ushort_t*)alloc(szWg);
    ushort_t* WdgPkH  = (ushort_t*)alloc(szWdg);
    ushort_t* WaePkH  = (ushort_t*)alloc(szWae);
    ushort_t* xhPkH   = (ushort_t*)alloc(szXh);
    ushort_t* xhPkL   = (ushort_t*)alloc(szXh);
    ushort_t* hseqPkH = (ushort_t*)alloc(szHseq);
    ushort_t* hseqPkL = (ushort_t*)alloc(szHseq);
    float*    cbuf    = (float*)alloc((size_t)Bb * Hh * 4);
    float*    dgb     = (float*)alloc((size_t)Bb * 1024 * 4);
    float*    S       = (float*)alloc((size_t)Bb * 1024 * 4); // fm + h0
    float*    bcomb   = (float*)alloc(4 * Hh * 4);

    auto tryAlloc = [&](size_t bytes) -> char* {
        size_t used = (size_t)(p - (char*)d_ws);
        size_t rounded = (bytes + 255) & ~(size_t)255;
        if (used + rounded > ws_size) return nullptr;
        return alloc(bytes);
    };
    ushort_t* WoutPkL = (ushort_t*)tryAlloc(szWout);
    ushort_t* WgPkL   = (ushort_t*)tryAlloc(szWg);
    ushort_t* WdgPkL  = (ushort_t*)tryAlloc(szWdg);
    ushort_t* imgLin  = (ushort_t*)tryAlloc(szImg);
    ushort_t* imgPk   = (ushort_t*)tryAlloc(szImg);

    float* fm  = S;
    float* h0b = S + Bb * ENCe;

    dim3 blk(256);
    const int NOSPLIT = 0x40000000;
    const int aFSh    = 16 * 512;

    // ---- one-time weight conversions (packed-fragment bf16) ----
    if (WoutPkL) convT_pk<true ><<<2500, blk, 0, stream>>>(W_out, Vv, 16, WoutPkH, WoutPkL, 16, 0, 0);
    else         convT_pk<false><<<2500, blk, 0, stream>>>(W_out, Vv, 16, WoutPkH, nullptr, 16, 0, 0);
    if (WgPkL) {
        convT_pk<true ><<<768, blk, 0, stream>>>(W_ih, 2048, 24, WgPkH, WgPkL, 40, 0, 0);
        convT_pk<true ><<<512, blk, 0, stream>>>(W_hh, 2048, 16, WgPkH, WgPkL, 40, 24, 0);
    } else {
        convT_pk<false><<<768, blk, 0, stream>>>(W_ih, 2048, 24, WgPkH, nullptr, 40, 0, 0);
        convT_pk<false><<<512, blk, 0, stream>>>(W_hh, 2048, 16, WgPkH, nullptr, 40, 24, 0);
    }
    if (WdgPkL) {
        convT_pk<true ><<<128, blk, 0, stream>>>(W_ad,   Hh, 16, WdgPkH, WdgPkL, 16, 0, 0);
        convT_pk<true ><<<128, blk, 0, stream>>>(W_gate, Hh, 16, WdgPkH, WdgPkL, 16, 0, 32);
    } else {
        convT_pk<false><<<128, blk, 0, stream>>>(W_ad,   Hh, 16, WdgPkH, nullptr, 16, 0, 0);
        convT_pk<false><<<128, blk, 0, stream>>>(W_gate, Hh, 16, WdgPkH, nullptr, 16, 0, 32);
    }
    convT_pk<false><<<128, blk, 0, stream>>>(W_ae, Hh, 16, WaePkH, nullptr, 16, 0, 0);

    bcomb_k<<<(4 * Hh + 255) / 256, blk, 0, stream>>>(b_ih, b_hh, bcomb);
    featmean_k<<<Bb, blk, 0, stream>>>(img, fm);

    gemm_k<32, 2, 4, 1, 0><<<dim3(Hh / 32, Bb / 64), blk, 0, stream>>>(
        fm, ENCe, W_h, Hh, b_h, h0b, Hh, Bb, Hh, ENCe);
    gemm_k<32, 2, 4, 1, 0><<<dim3(Hh / 32, Bb / 64), blk, 0, stream>>>(
        fm, ENCe, W_c, Hh, b_c, cbuf, Hh, Bb, Hh, ENCe);
    hconv_k<<<(Bb * Hh + 255) / 256, blk, 0, stream>>>(h0b, xhPkH, xhPkL);

    // enc_proj -> bf16 [B*L][512]
    if (imgPk && imgLin) {
        convimg_k<<<6272, blk, 0, stream>>>(img, imgLin, imgPk);
        mgemm_pk<4, 4, 0, 0, 1, true, false, true, true, true><<<dim3(784), blk, 0, stream>>>(
            imgPk, nullptr, aFSh, WaePkH, nullptr, aFSh, b_ae, nullptr, NOSPLIT,
            enc_hi, Hh, 0, 32, Hh, 16, 4);
    } else {
        if (imgLin) convbf_k<<<2048, blk, 0, stream>>>(img, imgLin, (long long)Bb * Ll * ENCe);
        gemm_k<64, 4, 4, 0, 1><<<dim3(Hh / 64, (Bb * Ll) / 64), blk, 0, stream>>>(
            img, ENCe, W_ae, Hh, b_ae, enc_hi, Hh, Bb * Ll, Hh, ENCe);
    }

    // ---- persistent 20-step loop (cooperative), fallback = per-phase ----
    LP P;
    P.WdgH = WdgPkH; P.WdgL = WdgPkL; P.WgH = WgPkH; P.WgL = WgPkL;
    P.enc = enc_hi; P.imgLin = imgLin; P.imgF = img;
    P.v_att = v_att; P.emb = emb; P.captions = captions;
    P.b_ad = b_ad; P.b_gate = b_gate; P.bcomb = bcomb;
    P.dgb = dgb; P.cbuf = cbuf; P.alphas = alphas;
    P.xhH = xhPkH; P.xhL = xhPkL; P.hsH = hseqPkH; P.hsL = hseqPkL;

    void* kargs[] = { (void*)&P };
    hipError_t ce = hipLaunchCooperativeKernel((const void*)loop_coop_k,
                                               dim3(256), dim3(256), kargs, 0, stream);
    if (ce != hipSuccess) {
        (void)hipGetLastError();  // clear error state
        for (int t = 0; t < Tt; ++t) {
            ph_dg_k<<<256, blk, 0, stream>>>(P);
            ph_attn_k<<<128, blk, 0, stream>>>(P, t);
            ph_gates_k<<<256, blk, 0, stream>>>(P, t);
        }
    }

    // ---- batched logits: [2560, 10000] -> out[b][t][v] ----
    if (WoutPkL)
        mgemm_pk<4, 4, 0, 0, 3, false, true, true, false, true><<<dim3(79 * 20), blk, 0, stream>>>(
            hseqPkH, hseqPkL, aFSh, WoutPkH, WoutPkL, aFSh,
            b_out, nullptr, NOSPLIT, out, (long long)Tt * Vv, (long long)Vv,
            625, Vv, 16, 20);
    else
        mgemm_pk<4, 4, 0, 0, 2, false, true, true, false, true><<<dim3(79 * 20), blk, 0, stream>>>(
            hseqPkH, hseqPkL, aFSh, WoutPkH, nullptr, aFSh,
            b_out, nullptr, NOSPLIT, out, (long long)Tt * Vv, (long long)Vv,
            625, Vv, 16, 20);
}

// Round 9
// 1363.568 us; speedup vs baseline: 4.1083x; 4.1083x over previous
//
#include <hip/hip_runtime.h>
#include <math.h>

typedef unsigned short ushort_t;
typedef __attribute__((ext_vector_type(8))) short bf16x8;
typedef __attribute__((ext_vector_type(4))) float f32x4;

constexpr int Bb  = 128;
constexpr int Ll  = 196;
constexpr int ENCe= 512;
constexpr int Hh  = 512;
constexpr int Ee  = 256;
constexpr int Vv  = 10000;
constexpr int Tt  = 20;

#define DEV __device__ __forceinline__

DEV float sigm_f(float x) { return 1.f / (1.f + __expf(-x)); }
DEV float tanh_f(float x) {
    x = fminf(fmaxf(x, -15.f), 15.f);
    float e = __expf(2.f * x);
    return (e - 1.f) / (e + 1.f);
}
DEV ushort_t f2bf(float v) {
    unsigned u = __float_as_uint(v);
    return (ushort_t)((u + 0x7FFFu + ((u >> 16) & 1u)) >> 16);
}
DEV float bf2f(ushort_t h) { return __uint_as_float(((unsigned)h) << 16); }

// Packed-fragment layout for a logical [R][K] bf16 matrix:
//   (r,k) -> ((r>>4)*KS + (k>>5))*512 + (((k>>3)&3)*16 + (r&15))*8 + (k&7)
DEV void store_xh(ushort_t* __restrict__ H, ushort_t* __restrict__ L,
                  int b, int k, float v)
{
    size_t idx = (((size_t)(b >> 4) * 40 + (k >> 5)) * 64
                  + ((k >> 3) & 3) * 16 + (b & 15)) * 8 + (k & 7);
    ushort_t hb = f2bf(v);
    H[idx] = hb;
    L[idx] = f2bf(v - bf2f(hb));
}

// ---------------------------------------------------------------------------
// fp32 tiled GEMM (h0/c0 + enc_proj fallback). OUTBF emits bf16.
// ---------------------------------------------------------------------------
template<int BN, int TM, int TN, int ACT1, int OUTBF>
__global__ __launch_bounds__(256)
void gemm_k(const float* __restrict__ A, int lda,
            const float* __restrict__ Wk, int ldw,
            const float* __restrict__ bias,
            void* __restrict__ Cv, long long ldc,
            int M, int N, int K)
{
    constexpr int BM = 64, BK = 16;
    constexpr int TX = BN / TN, TY = BM / TM;
    static_assert(TX * TY == 256, "bad tile config");
    __shared__ float As[BK][BM];
    __shared__ float Ws[BK][BN];

    const int tid = threadIdx.x;
    const int tx = tid % TX, ty = tid / TX;
    const int nb = blockIdx.x * BN, mb = blockIdx.y * BM;

    float acc[TM][TN] = {};
    const int am = tid >> 2;
    const int ak = (tid & 3) * 4;
    const int wn = tid % BN;
    const int wk0 = tid / BN;
    constexpr int WKSTEP = 256 / BN;

    for (int k0 = 0; k0 < K; k0 += BK) {
        float4 av = *(const float4*)&A[(size_t)(mb + am) * lda + k0 + ak];
        As[ak + 0][am] = av.x;
        As[ak + 1][am] = av.y;
        As[ak + 2][am] = av.z;
        As[ak + 3][am] = av.w;
        #pragma unroll
        for (int i = 0; i < BK / WKSTEP; ++i) {
            int kw = wk0 + i * WKSTEP;
            Ws[kw][wn] = (nb + wn < N) ? Wk[(size_t)(k0 + kw) * ldw + nb + wn] : 0.f;
        }
        __syncthreads();
        #pragma unroll
        for (int k = 0; k < BK; ++k) {
            float a[TM], w[TN];
            #pragma unroll
            for (int i = 0; i < TM; ++i) a[i] = As[k][ty * TM + i];
            #pragma unroll
            for (int j = 0; j < TN; ++j) w[j] = Ws[k][tx * TN + j];
            #pragma unroll
            for (int i = 0; i < TM; ++i)
                #pragma unroll
                for (int j = 0; j < TN; ++j)
                    acc[i][j] = fmaf(a[i], w[j], acc[i][j]);
        }
        __syncthreads();
    }

    #pragma unroll
    for (int i = 0; i < TM; ++i) {
        int m = mb + ty * TM + i;
        #pragma unroll
        for (int j = 0; j < TN; ++j) {
            int n = nb + tx * TN + j;
            if (n < N) {
                float v = acc[i][j];
                if (bias) v += bias[n];
                if (ACT1 == 1) v = tanh_f(v);
                if (OUTBF) ((ushort_t*)Cv)[(size_t)m * ldc + n] = f2bf(v);
                else       ((float*)Cv)[(size_t)m * ldc + n] = v;
            }
        }
    }
}

// ---------------------------------------------------------------------------
// Packed-fragment MFMA GEMM with register double-buffer prefetch.
// SPLIT: 1 = Ahi*Bhi; 2 = +Alo*Bhi; 3 = +Ahi*Blo.
// PERM: C row m = t*128+b -> out[b][t][:], via per-wave LDS transpose so each
//       4-lane group stores 256B contiguous (full lines, nontemporal f32x4).
// XSWZ: 1D grid, bijective XCD swizzle.
// ---------------------------------------------------------------------------
template<int MT, int NT, int ACT1, int ACT2, int SPLIT, bool OUTBF, bool PERM,
         bool XSWZ, bool NMINOR, bool W2D>
__global__ __launch_bounds__(256)
void mgemm_pk(const ushort_t* __restrict__ AH, const ushort_t* __restrict__ AL, int aFS,
              const ushort_t* __restrict__ BH, const ushort_t* __restrict__ BL, int bFS,
              const float* __restrict__ bias, const float* __restrict__ bias2, int N1,
              void* __restrict__ Cv, long long ldc, long long ldc2,
              int Nfrags, int Ntot, int nsteps, int bdiv)
{
    int bx, by;
    if (XSWZ) {
        int nwg = gridDim.x, orig = blockIdx.x;
        int xcd = orig & 7, idx = orig >> 3;
        int q = nwg >> 3, r = nwg & 7;
        int lin = (xcd < r ? xcd * (q + 1) : r * (q + 1) + (xcd - r) * q) + idx;
        int l1 = lin / bdiv, l2 = lin - l1 * bdiv;
        bx = NMINOR ? l2 : l1;
        by = NMINOR ? l1 : l2;
    } else { bx = blockIdx.x; by = blockIdx.y; }

    const int wv = threadIdx.x >> 6, lane = threadIdx.x & 63;
    int nf0, mf0;
    if (W2D) {
        nf0 = (bx * 2 + (wv & 1)) * NT;
        mf0 = by * (2 * MT) + (wv >> 1) * MT;
    } else {
        nf0 = (bx * 4 + wv) * NT;
        mf0 = by * MT;
    }
    if (nf0 >= Nfrags) return;
    const int col = lane & 15;
    const int lofs = lane * 8;

    const ushort_t *paH[MT], *paL[MT], *pbH[NT], *pbL[NT];
    #pragma unroll
    for (int mt = 0; mt < MT; ++mt) {
        paH[mt] = AH + (size_t)(mf0 + mt) * aFS + lofs;
        paL[mt] = (SPLIT >= 2) ? (AL + (size_t)(mf0 + mt) * aFS + lofs) : paH[mt];
    }
    #pragma unroll
    for (int ct = 0; ct < NT; ++ct) {
        int nf = nf0 + ct; if (nf > Nfrags - 1) nf = Nfrags - 1;
        pbH[ct] = BH + (size_t)nf * bFS + lofs;
        pbL[ct] = (SPLIT == 3) ? (BL + (size_t)nf * bFS + lofs) : pbH[ct];
    }

    f32x4 acc[MT][NT];
    #pragma unroll
    for (int mt = 0; mt < MT; ++mt)
        #pragma unroll
        for (int ct = 0; ct < NT; ++ct) acc[mt][ct] = (f32x4){0.f, 0.f, 0.f, 0.f};

    auto LOADF = [&](bf16x8 (&A0)[MT], bf16x8 (&A1)[MT],
                     bf16x8 (&B0)[NT], bf16x8 (&B1)[NT], int i) {
        size_t o = (size_t)i * 512;
        #pragma unroll
        for (int mt = 0; mt < MT; ++mt) {
            A0[mt] = *(const bf16x8*)(paH[mt] + o);
            if (SPLIT >= 2) A1[mt] = *(const bf16x8*)(paL[mt] + o);
        }
        #pragma unroll
        for (int ct = 0; ct < NT; ++ct) {
            B0[ct] = *(const bf16x8*)(pbH[ct] + o);
            if (SPLIT == 3) B1[ct] = *(const bf16x8*)(pbL[ct] + o);
        }
    };
    auto COMPF = [&](bf16x8 (&A0)[MT], bf16x8 (&A1)[MT],
                     bf16x8 (&B0)[NT], bf16x8 (&B1)[NT]) {
        #pragma unroll
        for (int mt = 0; mt < MT; ++mt)
            #pragma unroll
            for (int ct = 0; ct < NT; ++ct) {
                acc[mt][ct] = __builtin_amdgcn_mfma_f32_16x16x32_bf16(A0[mt], B0[ct], acc[mt][ct], 0, 0, 0);
                if (SPLIT >= 2)
                    acc[mt][ct] = __builtin_amdgcn_mfma_f32_16x16x32_bf16(A1[mt], B0[ct], acc[mt][ct], 0, 0, 0);
                if (SPLIT == 3)
                    acc[mt][ct] = __builtin_amdgcn_mfma_f32_16x16x32_bf16(A0[mt], B1[ct], acc[mt][ct], 0, 0, 0);
            }
    };

    bf16x8 xa0[MT], xa1[MT], xb0[NT], xb1[NT];
    bf16x8 ya0[MT], ya1[MT], yb0[NT], yb1[NT];
    LOADF(xa0, xa1, xb0, xb1, 0);
    for (int i = 0; i < nsteps; i += 2) {
        LOADF(ya0, ya1, yb0, yb1, i + 1);
        COMPF(xa0, xa1, xb0, xb1);
        if (i + 2 < nsteps) LOADF(xa0, xa1, xb0, xb1, i + 2);
        COMPF(ya0, ya1, yb0, yb1);
    }

    if constexpr (PERM) {
        // Per-wave LDS transpose epilogue: full-line coalesced output stores.
        __shared__ float tile[4][16 * 65];
        float* tw = tile[wv];
        const int r16w = (lane >> 4) * 4;   // row base for writes
        const int rrd  = lane >> 2;         // row for reads (0..15)
        const int ck   = lane & 3;          // chunk index = ct (0..3)
        #pragma unroll
        for (int mt = 0; mt < MT; ++mt) {
            #pragma unroll
            for (int ct = 0; ct < NT; ++ct) {
                const int nc = (nf0 + ct) * 16 + col;
                float bv = (bias && nc < Ntot) ? bias[nc] : 0.f;
                #pragma unroll
                for (int r = 0; r < 4; ++r)
                    tw[(r16w + r) * 65 + ct * 16 + col] = acc[mt][ct][r] + bv;
            }
            // wave-synchronous: same wave wrote, same wave reads
            if (nf0 + ck < Nfrags) {
                int grow = (mf0 + mt) * 16 + rrd;
                float* dst = (float*)Cv + (size_t)(grow & 127) * ldc
                             + (size_t)(grow >> 7) * ldc2 + (size_t)(nf0 + ck) * 16;
                #pragma unroll
                for (int q = 0; q < 4; ++q) {
                    f32x4 v4;
                    v4[0] = tw[rrd * 65 + ck * 16 + q * 4 + 0];
                    v4[1] = tw[rrd * 65 + ck * 16 + q * 4 + 1];
                    v4[2] = tw[rrd * 65 + ck * 16 + q * 4 + 2];
                    v4[3] = tw[rrd * 65 + ck * 16 + q * 4 + 3];
                    __builtin_nontemporal_store(v4, (f32x4*)(dst + q * 4));
                }
            }
        }
    } else {
        #pragma unroll
        for (int ct = 0; ct < NT; ++ct) {
            const int nc = (nf0 + ct) * 16 + col;
            if (nc >= Ntot) continue;
            const bool ns = ((nf0 + ct) * 16 >= N1);
            float bv = ns ? (bias2 ? bias2[nc - N1] : 0.f) : (bias ? bias[nc] : 0.f);
            const int act = ns ? ACT2 : ACT1;
            #pragma unroll
            for (int mt = 0; mt < MT; ++mt)
                #pragma unroll
                for (int r = 0; r < 4; ++r) {
                    int row = (mf0 + mt) * 16 + (lane >> 4) * 4 + r;
                    float v = acc[mt][ct][r] + bv;
                    if (act == 1)      v = tanh_f(v);
                    else if (act == 2) v = sigm_f(v);
                    size_t off = (size_t)row * ldc + nc;
                    if (OUTBF) ((ushort_t*)Cv)[off] = f2bf(v);
                    else       ((float*)Cv)[off] = v;
                }
        }
    }
}

// ---------------------------------------------------------------------------
// Weight transpose+convert into PACKED-FRAGMENT layout.
// ---------------------------------------------------------------------------
template<bool LO>
__global__ __launch_bounds__(256)
void convT_pk(const float* __restrict__ W, int N, int KSr,
              ushort_t* __restrict__ PH, ushort_t* __restrict__ PL,
              int KSfull, int ksOfs, int nfOfs)
{
    int tid = blockIdx.x * 256 + threadIdx.x;
    int lane = tid & 63;
    int rest = tid >> 6;
    int ks = rest % KSr;
    int nf = rest / KSr;
    const float* src = W + (size_t)(ks * 32 + ((lane >> 4) & 3) * 8) * N
                         + nf * 16 + (lane & 15);
    size_t dbase = (((size_t)(nf + nfOfs) * KSfull + ks + ksOfs) * 64 + lane) * 8;
    #pragma unroll
    for (int jj = 0; jj < 8; ++jj) {
        float v = src[(size_t)jj * N];
        ushort_t h = f2bf(v);
        PH[dbase + jj] = h;
        if (LO) PL[dbase + jj] = f2bf(v - bf2f(h));
    }
}

// img fp32 -> linear bf16 hi + packed bf16 hi
__global__ __launch_bounds__(256)
void convimg_k(const float* __restrict__ img, ushort_t* __restrict__ linH,
               ushort_t* __restrict__ pkH)
{
    int tid = blockIdx.x * 256 + threadIdx.x;
    int lane = tid & 63;
    int rest = tid >> 6;
    int ks = rest & 15, rf = rest >> 4;
    int r = rf * 16 + (lane & 15);
    int k = ks * 32 + ((lane >> 4) & 3) * 8;
    const float* src = img + (size_t)r * 512 + k;
    ushort_t* ld = linH + (size_t)r * 512 + k;
    size_t pidx = (((size_t)rf * 16 + ks) * 64 + lane) * 8;
    #pragma unroll
    for (int jj = 0; jj < 8; ++jj) {
        ushort_t h = f2bf(src[jj]);
        ld[jj] = h;
        pkH[pidx + jj] = h;
    }
}

__global__ void convbf_k(const float* __restrict__ src, ushort_t* __restrict__ dst,
                         long long n)
{
    long long i = (long long)(blockIdx.x * 256 + threadIdx.x) * 4;
    long long stride = (long long)gridDim.x * 1024;
    for (; i + 3 < n; i += stride) {
        float4 v = *(const float4*)&src[i];
        dst[i + 0] = f2bf(v.x); dst[i + 1] = f2bf(v.y);
        dst[i + 2] = f2bf(v.z); dst[i + 3] = f2bf(v.w);
    }
}

__global__ __launch_bounds__(256)
void featmean_k(const float* __restrict__ img, float* __restrict__ fm)
{
    int b = blockIdx.x, tid = threadIdx.x;
    const float* base = img + (size_t)b * Ll * ENCe;
    for (int e = tid; e < ENCe; e += 256) {
        float s = 0.f;
        for (int l = 0; l < Ll; ++l) s += base[l * ENCe + e];
        fm[b * ENCe + e] = s * (1.f / (float)Ll);
    }
}

__global__ void bcomb_k(const float* __restrict__ bih, const float* __restrict__ bhh,
                        float* __restrict__ bc)
{
    int i = blockIdx.x * 256 + threadIdx.x;
    if (i < 4 * Hh) bc[i] = bih[i] + bhh[i];
}

__global__ void hconv_k(const float* __restrict__ h, ushort_t* __restrict__ xhi,
                        ushort_t* __restrict__ xlo)
{
    int i = blockIdx.x * 256 + threadIdx.x;
    if (i >= Bb * Hh) return;
    int b = i / Hh, j = i % Hh;
    store_xh(xhi, xlo, b, 768 + j, h[i]);
}

// ---------------------------------------------------------------------------
// Per-step loop kernels
// ---------------------------------------------------------------------------
struct LP {
    const ushort_t *WdgH, *WdgL, *WgH, *WgL, *enc, *imgLin;
    const float    *imgF, *v_att, *emb;
    const int      *captions;
    const float    *b_ad, *b_gate, *bcomb;
    float          *dgb, *cbuf, *alphas;
    ushort_t       *xhH, *xhL, *hsH, *hsL;
};

// dg = [h@W_ad + b_ad | sigmoid(h@W_gate + b_gate)]   (256 blocks, 2-wave K-split)
__global__ __launch_bounds__(256)
void ph_dg_k(LP P)
{
    __shared__ f32x4 part[2][64];
    const int beta = blockIdx.x;
    const int tid = threadIdx.x, wv = tid >> 6, lane = tid & 63;
    const int bx = beta >> 3, mf = beta & 7;
    const int nf = bx * 2 + (wv & 1), kh = wv >> 1;
    const int lofs = lane * 8;
    const bool blo = (P.WdgL != nullptr);

    const ushort_t* paH = P.xhH + ((size_t)mf * 40 + 24 + kh * 8) * 512 + lofs;
    const ushort_t* paL = P.xhL + ((size_t)mf * 40 + 24 + kh * 8) * 512 + lofs;
    const ushort_t* pbH = P.WdgH + ((size_t)nf * 16 + kh * 8) * 512 + lofs;
    const ushort_t* pbL = blo ? (P.WdgL + ((size_t)nf * 16 + kh * 8) * 512 + lofs) : pbH;

    f32x4 acc = (f32x4){0.f, 0.f, 0.f, 0.f};
    #pragma unroll
    for (int i = 0; i < 8; ++i) {
        size_t o = (size_t)i * 512;
        bf16x8 A0 = *(const bf16x8*)(paH + o);
        bf16x8 A1 = *(const bf16x8*)(paL + o);
        bf16x8 B0 = *(const bf16x8*)(pbH + o);
        acc = __builtin_amdgcn_mfma_f32_16x16x32_bf16(A0, B0, acc, 0, 0, 0);
        acc = __builtin_amdgcn_mfma_f32_16x16x32_bf16(A1, B0, acc, 0, 0, 0);
        if (blo) {
            bf16x8 B1 = *(const bf16x8*)(pbL + o);
            acc = __builtin_amdgcn_mfma_f32_16x16x32_bf16(A0, B1, acc, 0, 0, 0);
        }
    }

    if (kh == 1) part[wv & 1][lane] = acc;
    __syncthreads();
    if (kh == 0) {
        acc += part[wv & 1][lane];
        int n = nf * 16 + (lane & 15);
        float bv = (n < 512) ? P.b_ad[n] : P.b_gate[n - 512];
        #pragma unroll
        for (int r = 0; r < 4; ++r) {
            int row = mf * 16 + (lane >> 4) * 4 + r;
            float v = acc[r] + bv;
            if (n >= 512) v = sigm_f(v);
            P.dgb[row * 1024 + n] = v;
        }
    }
}

// Fused attention (128 blocks x 512 threads)
template<bool IMGBF>
__global__ __launch_bounds__(512)
void attn_fused_k(const ushort_t* __restrict__ enc, const float* __restrict__ dgb,
                  const float* __restrict__ v_att,
                  const ushort_t* __restrict__ img_bf, const float* __restrict__ img_f,
                  const float* __restrict__ emb, const int* __restrict__ captions,
                  float* __restrict__ alphas, long long alpha_stride,
                  ushort_t* __restrict__ xhi, ushort_t* __restrict__ xlo, int t)
{
    int b = blockIdx.x, tid = threadIdx.x;
    __shared__ float dp[Hh], va[Hh], es[Ll], red[8];

    dp[tid] = dgb[b * 1024 + tid];
    va[tid] = v_att[tid];
    __syncthreads();

    int wv = tid >> 6, ln = tid & 63;
    const ushort_t* ep = enc + (size_t)b * Ll * Hh;
    for (int l = wv; l < Ll; l += 8) {
        const ushort_t* row = ep + (size_t)l * Hh;
        float s = 0.f;
        #pragma unroll
        for (int r = 0; r < 8; ++r) {
            int k = r * 64 + ln;
            s += tanh_f(bf2f(row[k]) + dp[k]) * va[k];
        }
        #pragma unroll
        for (int o = 32; o; o >>= 1) s += __shfl_xor(s, o);
        if (ln == 0) es[l] = s;
    }
    __syncthreads();

    float v = (tid < Ll) ? es[tid] : -1e30f;
    float m = v;
    #pragma unroll
    for (int o = 32; o; o >>= 1) m = fmaxf(m, __shfl_xor(m, o));
    if (ln == 0) red[wv] = m;
    __syncthreads();
    m = red[0];
    #pragma unroll
    for (int i = 1; i < 8; ++i) m = fmaxf(m, red[i]);
    __syncthreads();
    float p = (tid < Ll) ? __expf(v - m) : 0.f;
    float s = p;
    #pragma unroll
    for (int o = 32; o; o >>= 1) s += __shfl_xor(s, o);
    if (ln == 0) red[wv] = s;
    __syncthreads();
    s = 0.f;
    #pragma unroll
    for (int i = 0; i < 8; ++i) s += red[i];
    float inv = 1.f / s;
    if (tid < Ll) {
        float a = p * inv;
        es[tid] = a;
        alphas[(size_t)b * alpha_stride + tid] = a;
    }
    if (tid < Ee) {
        float xv = emb[(size_t)captions[b * Tt + t] * Ee + tid];
        store_xh(xhi, xlo, b, tid, xv);
    }
    __syncthreads();

    int e = tid;
    float acc = 0.f;
    if (IMGBF) {
        const ushort_t* ib = img_bf + (size_t)b * Ll * ENCe + e;
        #pragma unroll 4
        for (int l = 0; l < Ll; ++l) acc = fmaf(es[l], bf2f(ib[(size_t)l * ENCe]), acc);
    } else {
        const float* ib = img_f + (size_t)b * Ll * ENCe + e;
        #pragma unroll 4
        for (int l = 0; l < Ll; ++l) acc = fmaf(es[l], ib[(size_t)l * ENCe], acc);
    }
    float xv = acc * dgb[b * 1024 + 512 + e];
    store_xh(xhi, xlo, b, 256 + e, xv);
}

// gates GEMM (4-wave K-split) + fused LSTM  (256 blocks: 32 jf x 8 mq)
__global__ __launch_bounds__(256)
void ph_gates_k(LP P, int t)
{
    __shared__ f32x4 part[3][4][64];
    const int beta = blockIdx.x;
    const int tid = threadIdx.x, wv = tid >> 6, lane = tid & 63;
    const int jf = beta & 31, mq = beta >> 5;
    const int ks0 = wv * 10, lofs = lane * 8;
    const bool blo = (P.WgL != nullptr);
    constexpr int FS = 40 * 512;

    const ushort_t* paH = P.xhH + ((size_t)mq * 40 + ks0) * 512 + lofs;
    const ushort_t* paL = P.xhL + ((size_t)mq * 40 + ks0) * 512 + lofs;
    const ushort_t *pbH[4], *pbL[4];
    #pragma unroll
    for (int g = 0; g < 4; ++g) {
        size_t off = (size_t)(g * 32 + jf) * FS + (size_t)ks0 * 512 + lofs;
        pbH[g] = P.WgH + off;
        pbL[g] = blo ? (P.WgL + off) : (P.WgH + off);
    }

    f32x4 acc[4];
    #pragma unroll
    for (int g = 0; g < 4; ++g) acc[g] = (f32x4){0.f, 0.f, 0.f, 0.f};

    auto LOADF = [&](bf16x8 (&A)[2], bf16x8 (&B)[4][2], int i) {
        size_t o = (size_t)i * 512;
        A[0] = *(const bf16x8*)(paH + o);
        A[1] = *(const bf16x8*)(paL + o);
        #pragma unroll
        for (int g = 0; g < 4; ++g) {
            B[g][0] = *(const bf16x8*)(pbH[g] + o);
            if (blo) B[g][1] = *(const bf16x8*)(pbL[g] + o);
        }
    };
    auto COMPF = [&](bf16x8 (&A)[2], bf16x8 (&B)[4][2]) {
        #pragma unroll
        for (int g = 0; g < 4; ++g) {
            acc[g] = __builtin_amdgcn_mfma_f32_16x16x32_bf16(A[0], B[g][0], acc[g], 0, 0, 0);
            acc[g] = __builtin_amdgcn_mfma_f32_16x16x32_bf16(A[1], B[g][0], acc[g], 0, 0, 0);
            if (blo)
                acc[g] = __builtin_amdgcn_mfma_f32_16x16x32_bf16(A[0], B[g][1], acc[g], 0, 0, 0);
        }
    };

    bf16x8 xA[2], xB[4][2], yA[2], yB[4][2];
    LOADF(xA, xB, 0);
    for (int i = 0; i < 10; i += 2) {
        LOADF(yA, yB, i + 1);
        COMPF(xA, xB);
        if (i + 2 < 10) LOADF(xA, xB, i + 2);
        COMPF(yA, yB);
    }

    if (wv > 0) {
        #pragma unroll
        for (int g = 0; g < 4; ++g) part[wv - 1][g][lane] = acc[g];
    }
    __syncthreads();
    if (wv == 0) {
        #pragma unroll
        for (int g = 0; g < 4; ++g) {
            acc[g] += part[0][g][lane];
            acc[g] += part[1][g][lane];
            acc[g] += part[2][g][lane];
        }
        const int j = jf * 16 + (lane & 15);
        float bi = P.bcomb[j], bf_ = P.bcomb[512 + j];
        float bg = P.bcomb[1024 + j], bo = P.bcomb[1536 + j];
        #pragma unroll
        for (int r = 0; r < 4; ++r) {
            int b = mq * 16 + (lane >> 4) * 4 + r;
            float ig = sigm_f(acc[0][r] + bi);
            float fg = sigm_f(acc[1][r] + bf_);
            float gg = tanh_f(acc[2][r] + bg);
            float og = sigm_f(acc[3][r] + bo);
            float cn = fg * P.cbuf[b * 512 + j] + ig * gg;
            P.cbuf[b * 512 + j] = cn;
            float hv = og * tanh_f(cn);
            store_xh(P.xhH, P.xhL, b, 768 + j, hv);
            ushort_t hb = f2bf(hv);
            size_t hidx = (((size_t)(t * 8 + (b >> 4)) * 16 + (j >> 5)) * 64
                           + ((j >> 3) & 3) * 16 + (b & 15)) * 8 + (j & 7);
            P.hsH[hidx] = hb;
            P.hsL[hidx] = f2bf(hv - bf2f(hb));
        }
    }
}

// ---------------------------------------------------------------------------
extern "C" void kernel_launch(void* const* d_in, const int* in_sizes, int n_in,
                              void* d_out, int out_size, void* d_ws, size_t ws_size,
                              hipStream_t stream)
{
    const float* img    = (const float*)d_in[0];
    const float* W_h    = (const float*)d_in[1];
    const float* b_h    = (const float*)d_in[2];
    const float* W_c    = (const float*)d_in[3];
    const float* b_c    = (const float*)d_in[4];
    const float* W_gate = (const float*)d_in[5];
    const float* b_gate = (const float*)d_in[6];
    const float* emb    = (const float*)d_in[7];
    const float* W_ae   = (const float*)d_in[8];
    const float* b_ae   = (const float*)d_in[9];
    const float* W_ad   = (const float*)d_in[10];
    const float* b_ad   = (const float*)d_in[11];
    const float* v_att  = (const float*)d_in[12];
    const float* W_ih   = (const float*)d_in[14];
    const float* b_ih   = (const float*)d_in[15];
    const float* W_hh   = (const float*)d_in[16];
    const float* b_hh   = (const float*)d_in[17];
    const float* W_out  = (const float*)d_in[18];
    const float* b_out  = (const float*)d_in[19];
    const int* captions = (const int*)d_in[20];

    float* out    = (float*)d_out;                       // [B,T,V]
    float* alphas = out + (size_t)Bb * Tt * Vv;          // [B,T,L]

    // ---- workspace allocator (256B aligned) ----
    char* p = (char*)d_ws;
    auto alloc = [&](size_t bytes) -> char* {
        char* r = p; p += (bytes + 255) & ~(size_t)255; return r;
    };
    const size_t szEnc   = (size_t)Bb * Ll * Hh * 2;
    const size_t szWout  = (size_t)625 * 16 * 512 * 2;
    const size_t szWg    = (size_t)128 * 40 * 512 * 2;
    const size_t szWdg   = (size_t)64 * 16 * 512 * 2;
    const size_t szWae   = (size_t)32 * 16 * 512 * 2;
    const size_t szXh    = (size_t)8 * 40 * 512 * 2;
    const size_t szHseq  = (size_t)160 * 16 * 512 * 2;
    const size_t szImg   = (size_t)Bb * Ll * ENCe * 2;

    ushort_t* enc_hi  = (ushort_t*)alloc(szEnc);
    ushort_t* WoutPkH = (ushort_t*)alloc(szWout);
    ushort_t* WgPkH   = (ushort_t*)alloc(szWg);
    ushort_t* WdgPkH  = (ushort_t*)alloc(szWdg);
    ushort_t* WaePkH  = (ushort_t*)alloc(szWae);
    ushort_t* xhPkH   = (ushort_t*)alloc(szXh);
    ushort_t* xhPkL   = (ushort_t*)alloc(szXh);
    ushort_t* hseqPkH = (ushort_t*)alloc(szHseq);
    ushort_t* hseqPkL = (ushort_t*)alloc(szHseq);
    float*    cbuf    = (float*)alloc((size_t)Bb * Hh * 4);
    float*    dgb     = (float*)alloc((size_t)Bb * 1024 * 4);
    float*    S       = (float*)alloc((size_t)Bb * 1024 * 4); // fm + h0
    float*    bcomb   = (float*)alloc(4 * Hh * 4);

    auto tryAlloc = [&](size_t bytes) -> char* {
        size_t used = (size_t)(p - (char*)d_ws);
        size_t rounded = (bytes + 255) & ~(size_t)255;
        if (used + rounded > ws_size) return nullptr;
        return alloc(bytes);
    };
    ushort_t* WoutPkL = (ushort_t*)tryAlloc(szWout);
    ushort_t* WgPkL   = (ushort_t*)tryAlloc(szWg);
    ushort_t* WdgPkL  = (ushort_t*)tryAlloc(szWdg);
    ushort_t* imgLin  = (ushort_t*)tryAlloc(szImg);
    ushort_t* imgPk   = (ushort_t*)tryAlloc(szImg);

    float* fm  = S;
    float* h0b = S + Bb * ENCe;

    dim3 blk(256);
    const int NOSPLIT = 0x40000000;
    const int aFSh    = 16 * 512;

    // ---- one-time weight conversions (packed-fragment bf16) ----
    if (WoutPkL) convT_pk<true ><<<2500, blk, 0, stream>>>(W_out, Vv, 16, WoutPkH, WoutPkL, 16, 0, 0);
    else         convT_pk<false><<<2500, blk, 0, stream>>>(W_out, Vv, 16, WoutPkH, nullptr, 16, 0, 0);
    if (WgPkL) {
        convT_pk<true ><<<768, blk, 0, stream>>>(W_ih, 2048, 24, WgPkH, WgPkL, 40, 0, 0);
        convT_pk<true ><<<512, blk, 0, stream>>>(W_hh, 2048, 16, WgPkH, WgPkL, 40, 24, 0);
    } else {
        convT_pk<false><<<768, blk, 0, stream>>>(W_ih, 2048, 24, WgPkH, nullptr, 40, 0, 0);
        convT_pk<false><<<512, blk, 0, stream>>>(W_hh, 2048, 16, WgPkH, nullptr, 40, 24, 0);
    }
    if (WdgPkL) {
        convT_pk<true ><<<128, blk, 0, stream>>>(W_ad,   Hh, 16, WdgPkH, WdgPkL, 16, 0, 0);
        convT_pk<true ><<<128, blk, 0, stream>>>(W_gate, Hh, 16, WdgPkH, WdgPkL, 16, 0, 32);
    } else {
        convT_pk<false><<<128, blk, 0, stream>>>(W_ad,   Hh, 16, WdgPkH, nullptr, 16, 0, 0);
        convT_pk<false><<<128, blk, 0, stream>>>(W_gate, Hh, 16, WdgPkH, nullptr, 16, 0, 32);
    }
    convT_pk<false><<<128, blk, 0, stream>>>(W_ae, Hh, 16, WaePkH, nullptr, 16, 0, 0);

    bcomb_k<<<(4 * Hh + 255) / 256, blk, 0, stream>>>(b_ih, b_hh, bcomb);
    featmean_k<<<Bb, blk, 0, stream>>>(img, fm);

    gemm_k<32, 2, 4, 1, 0><<<dim3(Hh / 32, Bb / 64), blk, 0, stream>>>(
        fm, ENCe, W_h, Hh, b_h, h0b, Hh, Bb, Hh, ENCe);
    gemm_k<32, 2, 4, 1, 0><<<dim3(Hh / 32, Bb / 64), blk, 0, stream>>>(
        fm, ENCe, W_c, Hh, b_c, cbuf, Hh, Bb, Hh, ENCe);
    hconv_k<<<(Bb * Hh + 255) / 256, blk, 0, stream>>>(h0b, xhPkH, xhPkL);

    // enc_proj -> bf16 [B*L][512]
    if (imgPk && imgLin) {
        convimg_k<<<6272, blk, 0, stream>>>(img, imgLin, imgPk);
        mgemm_pk<4, 4, 0, 0, 1, true, false, true, true, true><<<dim3(784), blk, 0, stream>>>(
            imgPk, nullptr, aFSh, WaePkH, nullptr, aFSh, b_ae, nullptr, NOSPLIT,
            enc_hi, Hh, 0, 32, Hh, 16, 4);
    } else {
        if (imgLin) convbf_k<<<2048, blk, 0, stream>>>(img, imgLin, (long long)Bb * Ll * ENCe);
        gemm_k<64, 4, 4, 0, 1><<<dim3(Hh / 64, (Bb * Ll) / 64), blk, 0, stream>>>(
            img, ENCe, W_ae, Hh, b_ae, enc_hi, Hh, Bb * Ll, Hh, ENCe);
    }

    // ---- 20-step loop: 3 dispatches per step ----
    LP P;
    P.WdgH = WdgPkH; P.WdgL = WdgPkL; P.WgH = WgPkH; P.WgL = WgPkL;
    P.enc = enc_hi; P.imgLin = imgLin; P.imgF = img;
    P.v_att = v_att; P.emb = emb; P.captions = captions;
    P.b_ad = b_ad; P.b_gate = b_gate; P.bcomb = bcomb;
    P.dgb = dgb; P.cbuf = cbuf; P.alphas = alphas;
    P.xhH = xhPkH; P.xhL = xhPkL; P.hsH = hseqPkH; P.hsL = hseqPkL;

    for (int t = 0; t < Tt; ++t) {
        ph_dg_k<<<256, blk, 0, stream>>>(P);
        if (imgLin)
            attn_fused_k<true ><<<Bb, dim3(512), 0, stream>>>(
                enc_hi, dgb, v_att, imgLin, nullptr, emb, captions,
                alphas + (size_t)t * Ll, (long long)Tt * Ll, xhPkH, xhPkL, t);
        else
            attn_fused_k<false><<<Bb, dim3(512), 0, stream>>>(
                enc_hi, dgb, v_att, nullptr, img, emb, captions,
                alphas + (size_t)t * Ll, (long long)Tt * Ll, xhPkH, xhPkL, t);
        ph_gates_k<<<256, blk, 0, stream>>>(P, t);
    }

    // ---- batched logits: [2560, 10000] -> out[b][t][v] ----
    if (WoutPkL)
        mgemm_pk<4, 4, 0, 0, 3, false, true, true, false, true><<<dim3(79 * 20), blk, 0, stream>>>(
            hseqPkH, hseqPkL, aFSh, WoutPkH, WoutPkL, aFSh,
            b_out, nullptr, NOSPLIT, out, (long long)Tt * Vv, (long long)Vv,
            625, Vv, 16, 20);
    else
        mgemm_pk<4, 4, 0, 0, 2, false, true, true, false, true><<<dim3(79 * 20), blk, 0, stream>>>(
            hseqPkH, hseqPkL, aFSh, WoutPkH, nullptr, aFSh,
            b_out, nullptr, NOSPLIT, out, (long long)Tt * Vv, (long long)Vv,
            625, Vv, 16, 20);
}